// Round 1
// baseline (2814.290 us; speedup 1.0000x reference)
//
#include <hip/hip_runtime.h>
#include <math.h>

#define TT 2048
#define UU 64
#define BB 256
#define NTHR 128        // 2 waves: wave0 = layer-0 producer, wave1 = layer-1 consumer
#define CH 16           // timesteps per chunk (one barrier per chunk)
#define NCH (TT / CH)   // 128 chunks -> 128 barriers total (vs 2050 before)
#define NSLOT (2 * CH)  // 32-slot double-buffered h ring

typedef float v2f __attribute__((ext_vector_type(2)));
typedef float v4f __attribute__((ext_vector_type(4)));

// Fast activations on v_exp_f32 / v_rcp_f32 (~1e-7 abs err; threshold 3.45e-6;
// validated at absmax 9.5e-7 in earlier rounds).
__device__ __forceinline__ float frcp(float x) { return __builtin_amdgcn_rcpf(x); }
__device__ __forceinline__ float fsigmoid(float x) { return frcp(1.0f + __expf(-x)); }
__device__ __forceinline__ float ftanh(float x) { return 1.0f - 2.0f * frcp(1.0f + __expf(2.0f * x)); }

// Opaque pin: blocks LLVM from rematerializing/reloading the weight regs
// inside the loop (earlier-round evidence: without it weights were re-read
// from L2 every step).
#define PIN2(v) asm volatile("" : "+v"(v))

// Packed dual-FMA: a.{x,y} += h.{x,y} * w.{x,y}  (one VOP3P instruction,
// halves the matvec issue count vs scalar v_fma).
__device__ __forceinline__ void pkfma(v2f& a, v2f h, v2f w) {
    asm("v_pk_fma_f32 %0, %1, %2, %0" : "+v"(a) : "v"(h), "v"(w));
}

// One block per batch element (256 blocks = 1/CU), 2 waves.
//
// Wave 0 (producer, layer 0): lane u owns unit u = ALL FOUR gate columns
//   {u, 64+u, 128+u, 192+u} of W0 (256 weights/lane as 128 pinned float2
//   (i,j)/(f,o) pairs). The matvec z = h·W0 runs entirely in registers:
//   h is broadcast by ONE ds_write_b64 of the (h,h) splat + 32
//   uniform-address ds_read_b128 (hardware broadcast, conflict-free), and
//   accumulated with 128 v_pk_fma_f32 in 8 chains x 16 deep. z never
//   touches LDS; no per-step barrier exists at all. The step's serial
//   chain is: act -> splat write -> lgkm -> broadcast reads -> 128 pk_fma.
//
// Wave 1 (consumer, layer 1 + dense): processes h in chunks of CH=16 steps
//   from the 32-slot ring, one __syncthreads per chunk (double buffer:
//   producer writes chunk k+1 while consumer reads chunk k; slots of chunk
//   k are only overwritten in chunk k+2, i.e. after the consumer passed the
//   next barrier). Consumer needs ~5.5k cyc/chunk vs producer ~8k -> never
//   stalls the producer. Both waves execute exactly 1 + NCH barriers.
__global__ __launch_bounds__(NTHR, 1) void lstm_ts_kernel(
    const float* __restrict__ x, const float* __restrict__ W0,
    const float* __restrict__ b0, const float* __restrict__ W1,
    const float* __restrict__ b1, const float* __restrict__ Wd,
    const float* __restrict__ bd, float* __restrict__ out)
{
    __shared__ __align__(16) float xbuf[TT];
    __shared__ __align__(16) float ring[NSLOT][2 * UU];  // (h,h) splat pairs
    __shared__ float red[2];

    const int tid = threadIdx.x;
    const int wid = tid >> 6;
    const int u = tid & 63;
    const int b = blockIdx.x;
    const float* xrow = x + b * TT;
    float* outrow = out + b * TT;

    // ---- prologue: stage x, sum of squares over T (both waves) ----
    float ss = 0.f;
    for (int i = tid; i < TT; i += NTHR) {
        float v = xrow[i];
        xbuf[i] = v;
        ss += v * v;
    }
    #pragma unroll
    for (int m = 1; m < 64; m <<= 1) ss += __shfl_xor(ss, m, 64);
    if (u == 0) red[wid] = ss;
    __syncthreads();  // B0

    if (wid == 0) {
        // ================= PRODUCER: layer-0 LSTM, one wave =================
        const float sq = red[0] + red[1];
        const float scale = 1.0f / sqrtf(fmaxf(sq, 1e-12f));  // precise, once

        // 128 float2 weight pairs = 256 VGPRs, pinned against remat/spill.
        v2f wij[UU], wfo[UU];
        #pragma unroll
        for (int k = 0; k < UU; ++k) {
            const float* r = W0 + (1 + k) * 256;
            wij[k].x = r[u];       wij[k].y = r[64 + u];
            wfo[k].x = r[128 + u]; wfo[k].y = r[192 + u];
            PIN2(wij[k]); PIN2(wfo[k]);
        }
        const float wxi = W0[u] * scale,       wxj = W0[64 + u] * scale;
        const float wxf = W0[128 + u] * scale, wxo = W0[192 + u] * scale;
        const float bci = b0[u],       bcj = b0[64 + u];
        const float bcf = b0[128 + u], bco = b0[192 + u];

        // h_{-1} = 0 lives in slot NSLOT-1 (step t reads slot (t-1)&31).
        ring[NSLOT - 1][2 * u]     = 0.f;
        ring[NSLOT - 1][2 * u + 1] = 0.f;

        float c0 = 0.f;

        for (int t = 0; t < TT; ++t) {
            const float xr = xbuf[t];  // uniform broadcast read

            // acc chains: 4 for (i,j), 4 for (f,o); x-term folded into chain 0
            v2f aij[4], afo[4];
            aij[0].x = fmaf(xr, wxi, bci); aij[0].y = fmaf(xr, wxj, bcj);
            afo[0].x = fmaf(xr, wxf, bcf); afo[0].y = fmaf(xr, wxo, bco);
            #pragma unroll
            for (int q = 1; q < 4; ++q) {
                aij[q].x = 0.f; aij[q].y = 0.f;
                afo[q].x = 0.f; afo[q].y = 0.f;
            }

            // ---- matvec: 32 broadcast b128 reads + 128 v_pk_fma_f32 ----
            const float* hs = ring[(t + NSLOT - 1) & (NSLOT - 1)];
            #pragma unroll
            for (int kk = 0; kk < 32; ++kk) {
                v4f hv = *(const v4f*)(hs + 4 * kk);  // (h2k,h2k,h2k+1,h2k+1)
                v2f hlo = __builtin_shufflevector(hv, hv, 0, 1);
                v2f hhi = __builtin_shufflevector(hv, hv, 2, 3);
                pkfma(aij[kk & 3], hlo, wij[2 * kk]);
                pkfma(afo[kk & 3], hlo, wfo[2 * kk]);
                pkfma(aij[kk & 3], hhi, wij[2 * kk + 1]);
                pkfma(afo[kk & 3], hhi, wfo[2 * kk + 1]);
            }
            v2f zij = (aij[0] + aij[1]) + (aij[2] + aij[3]);
            v2f zfo = (afo[0] + afo[1]) + (afo[2] + afo[3]);

            // ---- unit update, z never left registers ----
            c0 = fsigmoid(zfo.x + 1.0f) * c0 + fsigmoid(zij.x) * ftanh(zij.y);
            const float h = fsigmoid(zfo.y) * ftanh(c0);

            // publish (h,h) splat: feeds next step's broadcast AND consumer
            v2f hh; hh.x = h; hh.y = h;
            *(v2f*)(&ring[t & (NSLOT - 1)][2 * u]) = hh;

            if ((t & (CH - 1)) == (CH - 1)) __syncthreads();  // 1 per chunk
        }
    } else {
        // ================= CONSUMER: layer 1 + dense + store =================
        const float w1v0 = W1[u * 4 + 0], w1v1 = W1[u * 4 + 1];
        const float w1v2 = W1[u * 4 + 2], w1v3 = W1[u * 4 + 3];
        const float w1h0 = W1[256], w1h1 = W1[257], w1h2 = W1[258], w1h3 = W1[259];
        const float b10 = b1[0], b11 = b1[1], b12 = b1[2], b13 = b1[3];
        const float wd = Wd[0], bdv = bd[0];

        float c1 = 0.f, h1 = 0.f, oval = 0.f;

        for (int k2 = 0; k2 < NCH; ++k2) {
            __syncthreads();  // chunk k2 is now fully in the ring
            const int sbase = k2 * CH;
            for (int si = 0; si < CH; ++si) {
                const int s = sbase + si;
                const float hu = ring[s & (NSLOT - 1)][2 * u];  // stride-8B: 2-way, free
                float p0 = hu * w1v0, p1 = hu * w1v1, p2 = hu * w1v2, p3 = hu * w1v3;
                #pragma unroll
                for (int m = 1; m < 64; m <<= 1) {
                    p0 += __shfl_xor(p0, m, 64);
                    p1 += __shfl_xor(p1, m, 64);
                    p2 += __shfl_xor(p2, m, 64);
                    p3 += __shfl_xor(p3, m, 64);
                }
                const float z1i = p0 + fmaf(h1, w1h0, b10);
                const float z1j = p1 + fmaf(h1, w1h1, b11);
                const float z1f = p2 + fmaf(h1, w1h2, b12);
                const float z1o = p3 + fmaf(h1, w1h3, b13);
                c1 = fsigmoid(z1f + 1.0f) * c1 + fsigmoid(z1i) * ftanh(z1j);
                h1 = fsigmoid(z1o) * ftanh(c1);
                const float ov = fmaf(h1, wd, bdv);
                if ((s & 63) == u) oval = ov;
                if ((s & 63) == 63) outrow[(s & ~63) + u] = oval;
            }
        }
    }
}

extern "C" void kernel_launch(void* const* d_in, const int* in_sizes, int n_in,
                              void* d_out, int out_size, void* d_ws, size_t ws_size,
                              hipStream_t stream) {
    const float* x  = (const float*)d_in[0];
    const float* W0 = (const float*)d_in[1];
    const float* b0 = (const float*)d_in[2];
    const float* W1 = (const float*)d_in[3];
    const float* b1 = (const float*)d_in[4];
    const float* Wd = (const float*)d_in[5];
    const float* bd = (const float*)d_in[6];
    float* out = (float*)d_out;
    lstm_ts_kernel<<<BB, NTHR, 0, stream>>>(x, W0, b0, W1, b1, Wd, bd, out);
}